// Round 2
// baseline (1128.354 us; speedup 1.0000x reference)
//
#include <hip/hip_runtime.h>
#include <math.h>

#define HDIM 2048
#define NEXP 8
#define IDIM 16
#define N_EI 128      // NEXP * IDIM
#define TB 32         // tokens per block
#define NTHREADS 256

__global__ __launch_bounds__(NTHREADS) void moe_fused_kernel(
    const float* __restrict__ x,    // [T, H]
    const float* __restrict__ rw,   // [E, H]
    const float* __restrict__ dw,   // [E*I, H]  (E,I,H flattened)
    const float* __restrict__ uw,   // [E, H, I]
    float* __restrict__ out,        // [T, H]
    int T)
{
    __shared__ float logits_s[TB][NEXP];
    __shared__ float gate_s[TB][NEXP];
    __shared__ float a_s[TB][N_EI + 4];   // +4 keeps rows 16B-aligned, staggers banks

    const int tid = threadIdx.x;
    const int t0 = blockIdx.x * TB;

    // ---------------- Phase 1: router logits (fp32, exact) ----------------
    {
        const int t = tid >> 3;   // 0..31
        const int e = tid & 7;    // 0..7
        const float* __restrict__ xr = x + (size_t)(t0 + t) * HDIM;
        const float* __restrict__ wr = rw + (size_t)e * HDIM;
        float acc = 0.f;
        #pragma unroll 4
        for (int k = 0; k < HDIM; k += 4) {
            float4 xv = *(const float4*)(xr + k);
            float4 wv = *(const float4*)(wr + k);
            acc += xv.x * wv.x + xv.y * wv.y + xv.z * wv.z + xv.w * wv.w;
        }
        logits_s[t][e] = acc;
    }
    __syncthreads();

    // ---------------- softmax + top-2 -> gate ----------------
    if (tid < TB) {
        float w[NEXP];
        float m = logits_s[tid][0];
        #pragma unroll
        for (int e = 1; e < NEXP; ++e) m = fmaxf(m, logits_s[tid][e]);
        float s = 0.f;
        #pragma unroll
        for (int e = 0; e < NEXP; ++e) { w[e] = expf(logits_s[tid][e] - m); s += w[e]; }
        const float inv = 1.f / s;
        #pragma unroll
        for (int e = 0; e < NEXP; ++e) w[e] *= inv;
        // top-1 (ties -> lowest index, matches lax.top_k)
        int i1 = 0; float w1 = w[0];
        #pragma unroll
        for (int e = 1; e < NEXP; ++e) if (w[e] > w1) { w1 = w[e]; i1 = e; }
        // top-2
        int i2 = -1; float w2 = -1.f;
        #pragma unroll
        for (int e = 0; e < NEXP; ++e) if (e != i1 && w[e] > w2) { w2 = w[e]; i2 = e; }
        #pragma unroll
        for (int e = 0; e < NEXP; ++e)
            gate_s[tid][e] = (e == i1) ? w1 : ((e == i2) ? w2 : 0.f);
    }
    __syncthreads();

    // ---------------- Phase 2: down-proj (dense) + SiLU + gate -> a_s ----------------
    {
        const int tg = tid >> 4;   // 0..15 -> tokens tg and tg+16
        const int ng = tid & 15;   // 0..15 -> rows n0..n0+7 of dw
        const int n0 = ng * 8;
        const float* __restrict__ xa = x + (size_t)(t0 + tg) * HDIM;
        const float* __restrict__ xb = x + (size_t)(t0 + tg + 16) * HDIM;
        float acc_a[8], acc_b[8];
        #pragma unroll
        for (int j = 0; j < 8; ++j) { acc_a[j] = 0.f; acc_b[j] = 0.f; }

        for (int k = 0; k < HDIM; k += 4) {
            const float4 va = *(const float4*)(xa + k);
            const float4 vb = *(const float4*)(xb + k);
            #pragma unroll
            for (int j = 0; j < 8; ++j) {
                const float4 wv = *(const float4*)(dw + (size_t)(n0 + j) * HDIM + k);
                acc_a[j] += va.x * wv.x + va.y * wv.y + va.z * wv.z + va.w * wv.w;
                acc_b[j] += vb.x * wv.x + vb.y * wv.y + vb.z * wv.z + vb.w * wv.w;
            }
        }
        #pragma unroll
        for (int j = 0; j < 8; ++j) {
            const int n = n0 + j;
            const int e = n >> 4;
            const float ha = acc_a[j];
            const float hb = acc_b[j];
            const float sa = ha / (1.f + expf(-ha));   // silu
            const float sb = hb / (1.f + expf(-hb));
            a_s[tg][n]      = gate_s[tg][e] * sa;
            a_s[tg + 16][n] = gate_s[tg + 16][e] * sb;
        }
    }
    __syncthreads();

    // ---------------- Phase 3: up-proj  out[32,2048] = a_s[32,128] @ W2[128,2048] ----------------
    // W2[n = e*16+i, h] = uw[e*H*I + h*I + i]; i runs contiguous -> float4 along i.
    {
        const int tg = tid >> 4;   // 0..15 -> tokens tg, tg+16
        const int hg = tid & 15;   // h sub-group
        for (int hc = 0; hc < 16; ++hc) {
            const int hbase = hc * 128 + hg * 8;
            float acc_a[8], acc_b[8];
            #pragma unroll
            for (int j = 0; j < 8; ++j) { acc_a[j] = 0.f; acc_b[j] = 0.f; }

            #pragma unroll 4
            for (int n4 = 0; n4 < 32; ++n4) {
                const int n = n4 * 4;
                const int e = n >> 4;
                const int i0 = n & 15;
                const float4 a4 = *(const float4*)(&a_s[tg][n]);
                const float4 b4 = *(const float4*)(&a_s[tg + 16][n]);
                #pragma unroll
                for (int j = 0; j < 8; ++j) {
                    const float4 wv = *(const float4*)(uw + ((size_t)e * HDIM + (hbase + j)) * IDIM + i0);
                    acc_a[j] += a4.x * wv.x + a4.y * wv.y + a4.z * wv.z + a4.w * wv.w;
                    acc_b[j] += b4.x * wv.x + b4.y * wv.y + b4.z * wv.z + b4.w * wv.w;
                }
            }
            float* oa = out + (size_t)(t0 + tg) * HDIM + hbase;
            float* ob = out + (size_t)(t0 + tg + 16) * HDIM + hbase;
            *(float4*)(oa + 0) = make_float4(acc_a[0], acc_a[1], acc_a[2], acc_a[3]);
            *(float4*)(oa + 4) = make_float4(acc_a[4], acc_a[5], acc_a[6], acc_a[7]);
            *(float4*)(ob + 0) = make_float4(acc_b[0], acc_b[1], acc_b[2], acc_b[3]);
            *(float4*)(ob + 4) = make_float4(acc_b[4], acc_b[5], acc_b[6], acc_b[7]);
        }
    }
}

extern "C" void kernel_launch(void* const* d_in, const int* in_sizes, int n_in,
                              void* d_out, int out_size, void* d_ws, size_t ws_size,
                              hipStream_t stream) {
    const float* x  = (const float*)d_in[0];
    const float* rw = (const float*)d_in[1];
    const float* dw = (const float*)d_in[2];
    const float* uw = (const float*)d_in[3];
    float* out = (float*)d_out;

    const int T = in_sizes[0] / HDIM;       // 8192 tokens (B*T)
    const int grid = T / TB;                // 256 blocks

    moe_fused_kernel<<<grid, NTHREADS, 0, stream>>>(x, rw, dw, uw, out, T);
}

// Round 3
// 181.850 us; speedup vs baseline: 6.2048x; 6.2048x over previous
//
#include <hip/hip_runtime.h>
#include <math.h>

#define HDIM 2048
#define NEXP 8
#define IDIM 16
#define N_EI 128
#define TB   16        // tokens per main-kernel block

typedef __attribute__((ext_vector_type(8))) short bf16x8;
typedef __attribute__((ext_vector_type(4))) float f32x4;

// fp32 -> bf16 bits, round-to-nearest-even
static __device__ __forceinline__ short f2bf(float f) {
    union { float f; unsigned u; } v; v.f = f;
    unsigned r = v.u + 0x7fffu + ((v.u >> 16) & 1u);
    return (short)(r >> 16);
}

// ---------------------------------------------------------------------------
// Kernel 1: router (fp32 exact) -> gate_ws[T][8]; pack dw/uw to bf16 frag
// layout: B1p[(k>>3)*128*8 + n*8 + (k&7)] = dw[n][k]        (n = e*16+i, k over H)
//         B2p[(k2>>3)*2048*8 + h*8 + (k2&7)] = uw[e][h][i]  (k2 = e*16+i)
// ---------------------------------------------------------------------------
__global__ __launch_bounds__(256) void prep_kernel(
    const float* __restrict__ x, const float* __restrict__ rw,
    const float* __restrict__ dw, const float* __restrict__ uw,
    float* __restrict__ gate_ws, short* __restrict__ b1p, short* __restrict__ b2p,
    int T, int routerBlocks)
{
    const int bid = blockIdx.x;
    if (bid < routerBlocks) {
        // 4 waves per block, one token per wave
        const int wave = threadIdx.x >> 6, lane = threadIdx.x & 63;
        const int t = bid * 4 + wave;
        if (t >= T) return;
        const float* __restrict__ xr = x + (size_t)t * HDIM;
        float4 xv[8];
        #pragma unroll
        for (int j = 0; j < 8; ++j) xv[j] = *(const float4*)(xr + j * 256 + lane * 4);
        float logit[NEXP];
        #pragma unroll
        for (int e = 0; e < NEXP; ++e) {
            const float* __restrict__ wr = rw + (size_t)e * HDIM;
            float acc = 0.f;
            #pragma unroll
            for (int j = 0; j < 8; ++j) {
                float4 wv = *(const float4*)(wr + j * 256 + lane * 4);
                acc += xv[j].x * wv.x + xv[j].y * wv.y + xv[j].z * wv.z + xv[j].w * wv.w;
            }
            #pragma unroll
            for (int s = 1; s < 64; s <<= 1) acc += __shfl_xor(acc, s);
            logit[e] = acc;
        }
        if (lane == 0) {
            float m = logit[0];
            #pragma unroll
            for (int e = 1; e < NEXP; ++e) m = fmaxf(m, logit[e]);
            float w[NEXP], ssum = 0.f;
            #pragma unroll
            for (int e = 0; e < NEXP; ++e) { w[e] = expf(logit[e] - m); ssum += w[e]; }
            const float inv = 1.f / ssum;
            #pragma unroll
            for (int e = 0; e < NEXP; ++e) w[e] *= inv;
            int i1 = 0; float w1 = w[0];
            #pragma unroll
            for (int e = 1; e < NEXP; ++e) if (w[e] > w1) { w1 = w[e]; i1 = e; }
            int i2 = -1; float w2 = -1.f;
            #pragma unroll
            for (int e = 0; e < NEXP; ++e) if (e != i1 && w[e] > w2) { w2 = w[e]; i2 = e; }
            #pragma unroll
            for (int e = 0; e < NEXP; ++e)
                gate_ws[(size_t)t * NEXP + e] = (e == i1) ? w1 : ((e == i2) ? w2 : 0.f);
        }
    } else {
        // weight packing: 64 blocks x 256 threads x 16 elems = 262144 each
        const int wb = bid - routerBlocks;
        const int base = (wb * 256 + threadIdx.x) * 16;
        #pragma unroll 4
        for (int j = 0; j < 16; ++j) {
            const int d = base + j;
            {   // B1: d = (k>>3)*1024 + n*8 + (k&7)
                const int k = ((d >> 10) << 3) | (d & 7);
                const int n = (d >> 3) & 127;
                b1p[d] = f2bf(dw[(size_t)n * HDIM + k]);
            }
            {   // B2: d = (k2>>3)*16384 + h*8 + (k2&7)
                const int k2 = ((d >> 14) << 3) | (d & 7);
                const int h = (d >> 3) & 2047;
                b2p[d] = f2bf(uw[((size_t)(k2 >> 4) * HDIM + h) * IDIM + (k2 & 15)]);
            }
        }
    }
}

// ---------------------------------------------------------------------------
// Kernel 2: per 16-token tile: down GEMM (mfma bf16) -> silu*gate -> up GEMM
// 512 threads = 8 waves. Down: wave = (nq 0..3, kh 0..1). Up: wave = h-chunk.
// ---------------------------------------------------------------------------
__global__ __launch_bounds__(512) void moe_mfma_kernel(
    const float* __restrict__ x, const float* __restrict__ gate_ws,
    const short* __restrict__ b1p, const short* __restrict__ b2p,
    float* __restrict__ out, int T)
{
    __shared__ float h_part[TB][N_EI];   // 8 KB: kh=1 partial sums
    __shared__ short a_s[TB][N_EI];      // 4 KB: gated silu activations (bf16)
    __shared__ float gate_s[TB][NEXP];   // 512 B

    const int tid = threadIdx.x;
    const int w = tid >> 6, l = tid & 63;
    const int row = l & 15, kblk = l >> 4;   // frag coords
    const int t0 = blockIdx.x * TB;

    if (tid < TB * NEXP)
        gate_s[tid >> 3][tid & 7] = gate_ws[(size_t)(t0 + (tid >> 3)) * NEXP + (tid & 7)];
    __syncthreads();

    // ---------------- DOWN ----------------
    const int nq = w & 3, kh = w >> 2;
    const int n0 = nq * 32;
    f32x4 acc0 = {0.f, 0.f, 0.f, 0.f}, acc1 = {0.f, 0.f, 0.f, 0.f};
    const float* __restrict__ xrow = x + (size_t)(t0 + row) * HDIM;

    for (int s = 0; s < 32; ++s) {
        const int k0 = kh * 1024 + s * 32;
        const int ka = k0 + kblk * 8;
        // A-frag: 8 consecutive fp32 -> bf16 (lane: row=l&15, k=(l>>4)*8+j)
        float4 a0 = *(const float4*)(xrow + ka);
        float4 a1 = *(const float4*)(xrow + ka + 4);
        bf16x8 af;
        af[0] = f2bf(a0.x); af[1] = f2bf(a0.y); af[2] = f2bf(a0.z); af[3] = f2bf(a0.w);
        af[4] = f2bf(a1.x); af[5] = f2bf(a1.y); af[6] = f2bf(a1.z); af[7] = f2bf(a1.w);
        // B-frags straight from packed ws (L2-hot)
        const short* __restrict__ bbase = b1p + ((size_t)(k0 >> 3) + kblk) * 1024;
        bf16x8 bf0 = *(const bf16x8*)(bbase + (n0 + row) * 8);
        bf16x8 bf1 = *(const bf16x8*)(bbase + (n0 + 16 + row) * 8);
        acc0 = __builtin_amdgcn_mfma_f32_16x16x32_bf16(af, bf0, acc0, 0, 0, 0);
        acc1 = __builtin_amdgcn_mfma_f32_16x16x32_bf16(af, bf1, acc1, 0, 0, 0);
    }

    // C layout: token = kblk*4 + r, n = n0 (+16) + row
    if (kh == 1) {
        #pragma unroll
        for (int r = 0; r < 4; ++r) {
            h_part[kblk * 4 + r][n0 + row]      = acc0[r];
            h_part[kblk * 4 + r][n0 + 16 + row] = acc1[r];
        }
    }
    __syncthreads();
    if (kh == 0) {
        const int e0 = nq * 2, e1 = nq * 2 + 1;   // expert ids of the two n-frags
        #pragma unroll
        for (int r = 0; r < 4; ++r) {
            const int t = kblk * 4 + r;
            float hv0 = acc0[r] + h_part[t][n0 + row];
            float hv1 = acc1[r] + h_part[t][n0 + 16 + row];
            float sv0 = hv0 / (1.f + expf(-hv0)) * gate_s[t][e0];
            float sv1 = hv1 / (1.f + expf(-hv1)) * gate_s[t][e1];
            a_s[t][n0 + row]      = f2bf(sv0);
            a_s[t][n0 + 16 + row] = f2bf(sv1);
        }
    }
    __syncthreads();

    // ---------------- UP ----------------
    const int h0 = w * 256;   // each wave owns 256 output columns
    f32x4 acc[16];
    #pragma unroll
    for (int f = 0; f < 16; ++f) acc[f] = (f32x4){0.f, 0.f, 0.f, 0.f};

    for (int s = 0; s < 4; ++s) {
        bf16x8 af = *(const bf16x8*)(&a_s[row][s * 32 + kblk * 8]);
        const short* __restrict__ bbase = b2p + ((size_t)(s * 4) + kblk) * 16384;
        #pragma unroll
        for (int f = 0; f < 16; ++f) {
            bf16x8 bfr = *(const bf16x8*)(bbase + (size_t)(h0 + f * 16 + row) * 8);
            acc[f] = __builtin_amdgcn_mfma_f32_16x16x32_bf16(af, bfr, acc[f], 0, 0, 0);
        }
    }
    #pragma unroll
    for (int f = 0; f < 16; ++f) {
        #pragma unroll
        for (int r = 0; r < 4; ++r) {
            out[(size_t)(t0 + kblk * 4 + r) * HDIM + h0 + f * 16 + row] = acc[f][r];
        }
    }
}

extern "C" void kernel_launch(void* const* d_in, const int* in_sizes, int n_in,
                              void* d_out, int out_size, void* d_ws, size_t ws_size,
                              hipStream_t stream) {
    const float* x  = (const float*)d_in[0];
    const float* rw = (const float*)d_in[1];
    const float* dw = (const float*)d_in[2];
    const float* uw = (const float*)d_in[3];
    float* out = (float*)d_out;
    const int T = in_sizes[0] / HDIM;   // 8192 tokens

    // workspace layout
    float* gate_ws = (float*)d_ws;                          // T*8 f32 = 256 KB
    short* b1p = (short*)((char*)d_ws + (size_t)T * NEXP * 4);        // 512 KB
    short* b2p = (short*)((char*)d_ws + (size_t)T * NEXP * 4 + 262144 * 2);

    const int routerBlocks = T / 4;
    prep_kernel<<<routerBlocks + 64, 256, 0, stream>>>(x, rw, dw, uw,
                                                       gate_ws, b1p, b2p, T, routerBlocks);
    moe_mfma_kernel<<<T / TB, 512, 0, stream>>>(x, gate_ws, b1p, b2p, out, T);
}

// Round 5
// 180.364 us; speedup vs baseline: 6.2560x; 1.0082x over previous
//
#include <hip/hip_runtime.h>
#include <math.h>

#define HDIM 2048
#define NEXP 8
#define IDIM 16
#define N_EI 128
#define TB   16        // tokens per main-kernel block

typedef __attribute__((ext_vector_type(8))) short bf16x8;
typedef __attribute__((ext_vector_type(4))) float f32x4;

// fp32 -> bf16 bits, round-to-nearest-even
static __device__ __forceinline__ short f2bf(float f) {
    union { float f; unsigned u; } v; v.f = f;
    unsigned r = v.u + 0x7fffu + ((v.u >> 16) & 1u);
    return (short)(r >> 16);
}

// ---------------------------------------------------------------------------
// Kernel 1: router (fp32 exact, wave per token) -> gate_ws[T][8];
// vectorized pack of dw/uw to bf16 fragment layout:
//   b1p[(kb*128 + n)*8 + j]  = dw[n][kb*8 + j]          kb = k>>3
//   b2p[(k2b*2048 + h)*8 + j] = uw[e][h][i0 + j]         k2b = k2>>3, e=k2b>>1,
//                                                        i0=(k2b&1)*8
// ---------------------------------------------------------------------------
__global__ __launch_bounds__(256) void prep_kernel(
    const float* __restrict__ x, const float* __restrict__ rw,
    const float* __restrict__ dw, const float* __restrict__ uw,
    float* __restrict__ gate_ws, short* __restrict__ b1p, short* __restrict__ b2p,
    int T, int routerBlocks)
{
    const int bid = blockIdx.x;
    if (bid < routerBlocks) {
        // 4 waves per block, one token per wave; lanes split K (coalesced)
        const int wave = threadIdx.x >> 6, lane = threadIdx.x & 63;
        const int t = bid * 4 + wave;
        if (t >= T) return;
        const float* __restrict__ xr = x + (size_t)t * HDIM;
        float4 xv[8];
        #pragma unroll
        for (int j = 0; j < 8; ++j) xv[j] = *(const float4*)(xr + j * 256 + lane * 4);
        float logit[NEXP];
        #pragma unroll
        for (int e = 0; e < NEXP; ++e) {
            const float* __restrict__ wr = rw + (size_t)e * HDIM;
            float acc = 0.f;
            #pragma unroll
            for (int j = 0; j < 8; ++j) {
                float4 wv = *(const float4*)(wr + j * 256 + lane * 4);
                acc += xv[j].x * wv.x + xv[j].y * wv.y + xv[j].z * wv.z + xv[j].w * wv.w;
            }
            #pragma unroll
            for (int s = 1; s < 64; s <<= 1) acc += __shfl_xor(acc, s);
            logit[e] = acc;
        }
        if (lane == 0) {
            float m = logit[0];
            #pragma unroll
            for (int e = 1; e < NEXP; ++e) m = fmaxf(m, logit[e]);
            float w[NEXP], ssum = 0.f;
            #pragma unroll
            for (int e = 0; e < NEXP; ++e) { w[e] = expf(logit[e] - m); ssum += w[e]; }
            const float inv = 1.f / ssum;
            #pragma unroll
            for (int e = 0; e < NEXP; ++e) w[e] *= inv;
            int i1 = 0; float w1 = w[0];
            #pragma unroll
            for (int e = 1; e < NEXP; ++e) if (w[e] > w1) { w1 = w[e]; i1 = e; }
            int i2 = -1; float w2 = -1.f;
            #pragma unroll
            for (int e = 0; e < NEXP; ++e) if (e != i1 && w[e] > w2) { w2 = w[e]; i2 = e; }
            #pragma unroll
            for (int e = 0; e < NEXP; ++e)
                gate_ws[(size_t)t * NEXP + e] = (e == i1) ? w1 : ((e == i2) ? w2 : 0.f);
        }
    } else {
        // fully vectorized packing: 256 blocks x 256 threads, 1 short8 each side
        const int id = (bid - routerBlocks) * 256 + threadIdx.x;   // 0..65535
        float4 v0, v1;
        short* dst;
        if (id < 32768) {            // b1p: id = kb*128 + n
            const int kb = id >> 7, n = id & 127;
            const float* __restrict__ src = dw + (size_t)n * HDIM + kb * 8;
            v0 = *(const float4*)(src);
            v1 = *(const float4*)(src + 4);
            dst = b1p + (size_t)id * 8;
        } else {                     // b2p: id2 = k2b*2048 + h
            const int id2 = id - 32768;
            const int k2b = id2 >> 11, h = id2 & 2047;
            const int e = k2b >> 1, i0 = (k2b & 1) * 8;
            const float* __restrict__ src = uw + ((size_t)e * HDIM + h) * IDIM + i0;
            v0 = *(const float4*)(src);
            v1 = *(const float4*)(src + 4);
            dst = b2p + (size_t)id2 * 8;
        }
        bf16x8 p;
        p[0] = f2bf(v0.x); p[1] = f2bf(v0.y); p[2] = f2bf(v0.z); p[3] = f2bf(v0.w);
        p[4] = f2bf(v1.x); p[5] = f2bf(v1.y); p[6] = f2bf(v1.z); p[7] = f2bf(v1.w);
        *(bf16x8*)dst = p;
    }
}

// ---------------------------------------------------------------------------
// Kernel 2: per 16-token tile. Operand-swapped MFMA (A=weights, B=acts^T):
//   down: D[n][token]  -> silu*gate -> a_s (8B LDS writes)
//   up:   D[h][token]  -> lane holds 4 consecutive h -> float4 stores
// ---------------------------------------------------------------------------
__global__ __launch_bounds__(512) void moe_mfma_kernel(
    const float* __restrict__ x, const float* __restrict__ gate_ws,
    const short* __restrict__ b1p, const short* __restrict__ b2p,
    float* __restrict__ out, int T)
{
    __shared__ float h_part[TB][132];    // stride 132 dw (≡4 mod 32): 2-way, free
    __shared__ short a_s[TB][136];       // stride 136 sh = 68 dw (≡4 mod 32)
    __shared__ float gate_s[TB][NEXP];

    const int tid = threadIdx.x;
    const int w = tid >> 6, l = tid & 63;
    const int c = l & 15;                // MFMA col lane -> token
    const int kblk = l >> 4;             // k-block / D row-group
    const int t0 = blockIdx.x * TB;

    if (tid < TB * NEXP)
        gate_s[tid >> 3][tid & 7] = gate_ws[(size_t)(t0 + (tid >> 3)) * NEXP + (tid & 7)];
    __syncthreads();

    // ---------------- DOWN: D[n][token] ----------------
    const int nq = w & 3, kh = w >> 2;
    const int n0 = nq * 32;
    f32x4 acc0 = {0.f, 0.f, 0.f, 0.f}, acc1 = {0.f, 0.f, 0.f, 0.f};
    const float* __restrict__ xrow = x + (size_t)(t0 + c) * HDIM;   // B-frag: col=token

    for (int s = 0; s < 32; ++s) {
        const int k0 = kh * 1024 + s * 32;
        const int ka = k0 + kblk * 8;
        float4 a0 = *(const float4*)(xrow + ka);
        float4 a1 = *(const float4*)(xrow + ka + 4);
        bf16x8 xf;
        xf[0] = f2bf(a0.x); xf[1] = f2bf(a0.y); xf[2] = f2bf(a0.z); xf[3] = f2bf(a0.w);
        xf[4] = f2bf(a1.x); xf[5] = f2bf(a1.y); xf[6] = f2bf(a1.z); xf[7] = f2bf(a1.w);
        const short* __restrict__ bbase = b1p + ((size_t)(k0 >> 3) + kblk) * 1024;
        bf16x8 wf0 = *(const bf16x8*)(bbase + (n0 + c) * 8);        // A-frag: row=n
        bf16x8 wf1 = *(const bf16x8*)(bbase + (n0 + 16 + c) * 8);
        acc0 = __builtin_amdgcn_mfma_f32_16x16x32_bf16(wf0, xf, acc0, 0, 0, 0);
        acc1 = __builtin_amdgcn_mfma_f32_16x16x32_bf16(wf1, xf, acc1, 0, 0, 0);
    }

    // D: col=c=token, row=(l>>4)*4+r -> n = n0 (+16) + kblk*4 + r
    if (kh == 1) {
        *(f32x4*)&h_part[c][n0 + kblk * 4]      = acc0;
        *(f32x4*)&h_part[c][n0 + 16 + kblk * 4] = acc1;
    }
    __syncthreads();
    if (kh == 0) {
        const int e0 = nq * 2, e1 = nq * 2 + 1;
        const f32x4 hp0 = *(const f32x4*)&h_part[c][n0 + kblk * 4];
        const f32x4 hp1 = *(const f32x4*)&h_part[c][n0 + 16 + kblk * 4];
        const float g0 = gate_s[c][e0], g1 = gate_s[c][e1];
        short r0[4], r1[4];
        #pragma unroll
        for (int r = 0; r < 4; ++r) {
            const float h0v = acc0[r] + hp0[r];
            const float h1v = acc1[r] + hp1[r];
            r0[r] = f2bf(h0v / (1.f + expf(-h0v)) * g0);
            r1[r] = f2bf(h1v / (1.f + expf(-h1v)) * g1);
        }
        // 4 consecutive n -> single 8B write each
        *(uint2*)&a_s[c][n0 + kblk * 4]      = make_uint2(((unsigned short)r0[0]) | ((unsigned)(unsigned short)r0[1] << 16),
                                                          ((unsigned short)r0[2]) | ((unsigned)(unsigned short)r0[3] << 16));
        *(uint2*)&a_s[c][n0 + 16 + kblk * 4] = make_uint2(((unsigned short)r1[0]) | ((unsigned)(unsigned short)r1[1] << 16),
                                                          ((unsigned short)r1[2]) | ((unsigned)(unsigned short)r1[3] << 16));
    }
    __syncthreads();

    // ---------------- UP: D[h][token] ----------------
    const int h0 = w * 256;
    f32x4 acc[16];
    #pragma unroll
    for (int f = 0; f < 16; ++f) acc[f] = (f32x4){0.f, 0.f, 0.f, 0.f};

    for (int s = 0; s < 4; ++s) {
        bf16x8 af = *(const bf16x8*)(&a_s[c][s * 32 + kblk * 8]);   // B-frag: col=token
        const short* __restrict__ bbase = b2p + ((size_t)(s * 4) + kblk) * 16384;
        #pragma unroll
        for (int f = 0; f < 16; ++f) {
            bf16x8 wfr = *(const bf16x8*)(bbase + (size_t)(h0 + f * 16 + c) * 8);  // A-frag: row=h
            acc[f] = __builtin_amdgcn_mfma_f32_16x16x32_bf16(wfr, af, acc[f], 0, 0, 0);
        }
    }
    // lane holds 4 consecutive h (rows kblk*4+r) for token c -> float4 stores
    float* __restrict__ orow = out + (size_t)(t0 + c) * HDIM;
    #pragma unroll
    for (int f = 0; f < 16; ++f) {
        __builtin_nontemporal_store(acc[f], (f32x4*)(orow + h0 + f * 16 + kblk * 4));
    }
}

extern "C" void kernel_launch(void* const* d_in, const int* in_sizes, int n_in,
                              void* d_out, int out_size, void* d_ws, size_t ws_size,
                              hipStream_t stream) {
    const float* x  = (const float*)d_in[0];
    const float* rw = (const float*)d_in[1];
    const float* dw = (const float*)d_in[2];
    const float* uw = (const float*)d_in[3];
    float* out = (float*)d_out;
    const int T = in_sizes[0] / HDIM;   // 8192 tokens

    float* gate_ws = (float*)d_ws;                                      // 256 KB
    short* b1p = (short*)((char*)d_ws + (size_t)T * NEXP * 4);          // 512 KB
    short* b2p = (short*)((char*)d_ws + (size_t)T * NEXP * 4 + 524288); // 512 KB

    const int routerBlocks = T / 4;                 // 2048
    prep_kernel<<<routerBlocks + 256, 256, 0, stream>>>(x, rw, dw, uw,
                                                        gate_ws, b1p, b2p, T, routerBlocks);
    moe_mfma_kernel<<<T / TB, 512, 0, stream>>>(x, gate_ws, b1p, b2p, out, T);
}

// Round 7
// 172.484 us; speedup vs baseline: 6.5418x; 1.0457x over previous
//
#include <hip/hip_runtime.h>
#include <math.h>

#define HDIM 2048
#define NEXP 8
#define IDIM 16
#define N_EI 128
#define TB   32        // tokens per main-kernel block

typedef __attribute__((ext_vector_type(8))) short bf16x8;
typedef __attribute__((ext_vector_type(4))) float f32x4;

// fp32 -> bf16 bits, round-to-nearest-even
static __device__ __forceinline__ short f2bf(float f) {
    union { float f; unsigned u; } v; v.f = f;
    unsigned r = v.u + 0x7fffu + ((v.u >> 16) & 1u);
    return (short)(r >> 16);
}

// ---------------------------------------------------------------------------
// Kernel 1 (fused prep):
//   blocks [0, routerBlocks)               : router fp32 -> gate_ws[T][8]
//   blocks [routerBlocks, +256)            : pack dw/uw -> b1p/b2p (bf16 frags)
//   blocks [routerBlocks+256, +xcvtBlocks) : x fp32 -> x_bf (row-major bf16)
// ---------------------------------------------------------------------------
__global__ __launch_bounds__(256) void prep_kernel(
    const float* __restrict__ x, const float* __restrict__ rw,
    const float* __restrict__ dw, const float* __restrict__ uw,
    float* __restrict__ gate_ws, short* __restrict__ b1p, short* __restrict__ b2p,
    short* __restrict__ x_bf, int T, int routerBlocks)
{
    const int bid = blockIdx.x;
    if (bid < routerBlocks) {
        // wave per token; lanes split K (coalesced)
        const int wave = threadIdx.x >> 6, lane = threadIdx.x & 63;
        const int t = bid * 4 + wave;
        const float* __restrict__ xr = x + (size_t)t * HDIM;
        float4 xv[8];
        #pragma unroll
        for (int j = 0; j < 8; ++j) xv[j] = *(const float4*)(xr + j * 256 + lane * 4);
        // all 8 expert partial dots first (independent)
        float accv[NEXP];
        #pragma unroll
        for (int e = 0; e < NEXP; ++e) {
            const float* __restrict__ wr = rw + (size_t)e * HDIM;
            float acc = 0.f;
            #pragma unroll
            for (int j = 0; j < 8; ++j) {
                float4 wv = *(const float4*)(wr + j * 256 + lane * 4);
                acc += xv[j].x * wv.x + xv[j].y * wv.y + xv[j].z * wv.z + xv[j].w * wv.w;
            }
            accv[e] = acc;
        }
        // batched butterfly: 6 stages, 8 independent shuffles per stage
        #pragma unroll
        for (int s = 1; s < 64; s <<= 1) {
            #pragma unroll
            for (int e = 0; e < NEXP; ++e) accv[e] += __shfl_xor(accv[e], s);
        }
        if (lane == 0) {
            float m = accv[0];
            #pragma unroll
            for (int e = 1; e < NEXP; ++e) m = fmaxf(m, accv[e]);
            float w[NEXP], ssum = 0.f;
            #pragma unroll
            for (int e = 0; e < NEXP; ++e) { w[e] = expf(accv[e] - m); ssum += w[e]; }
            const float inv = 1.f / ssum;
            #pragma unroll
            for (int e = 0; e < NEXP; ++e) w[e] *= inv;
            int i1 = 0; float w1 = w[0];
            #pragma unroll
            for (int e = 1; e < NEXP; ++e) if (w[e] > w1) { w1 = w[e]; i1 = e; }
            int i2 = -1; float w2 = -1.f;
            #pragma unroll
            for (int e = 0; e < NEXP; ++e) if (e != i1 && w[e] > w2) { w2 = w[e]; i2 = e; }
            #pragma unroll
            for (int e = 0; e < NEXP; ++e)
                gate_ws[(size_t)t * NEXP + e] = (e == i1) ? w1 : ((e == i2) ? w2 : 0.f);
        }
    } else if (bid < routerBlocks + 256) {
        // vectorized packing: 1 short8 per thread per side
        const int id = (bid - routerBlocks) * 256 + threadIdx.x;   // 0..65535
        float4 v0, v1;
        short* dst;
        if (id < 32768) {            // b1p: id = kb*128 + n ; b1p[id*8+j] = dw[n][kb*8+j]
            const int kb = id >> 7, n = id & 127;
            const float* __restrict__ src = dw + (size_t)n * HDIM + kb * 8;
            v0 = *(const float4*)(src);
            v1 = *(const float4*)(src + 4);
            dst = b1p + (size_t)id * 8;
        } else {                     // b2p: id2 = k2b*2048 + h ; = uw[e][h][i0+j]
            const int id2 = id - 32768;
            const int k2b = id2 >> 11, h = id2 & 2047;
            const int e = k2b >> 1, i0 = (k2b & 1) * 8;
            const float* __restrict__ src = uw + ((size_t)e * HDIM + h) * IDIM + i0;
            v0 = *(const float4*)(src);
            v1 = *(const float4*)(src + 4);
            dst = b2p + (size_t)id2 * 8;
        }
        bf16x8 p;
        p[0] = f2bf(v0.x); p[1] = f2bf(v0.y); p[2] = f2bf(v0.z); p[3] = f2bf(v0.w);
        p[4] = f2bf(v1.x); p[5] = f2bf(v1.y); p[6] = f2bf(v1.z); p[7] = f2bf(v1.w);
        *(bf16x8*)dst = p;
    } else {
        // x -> bf16, 16 elems per thread
        const size_t gid = (size_t)(bid - routerBlocks - 256) * 256 + threadIdx.x;
        const size_t base = gid * 16;
        const float* __restrict__ src = x + base;
        float4 a = *(const float4*)(src);
        float4 b = *(const float4*)(src + 4);
        float4 c = *(const float4*)(src + 8);
        float4 d = *(const float4*)(src + 12);
        bf16x8 p0, p1;
        p0[0] = f2bf(a.x); p0[1] = f2bf(a.y); p0[2] = f2bf(a.z); p0[3] = f2bf(a.w);
        p0[4] = f2bf(b.x); p0[5] = f2bf(b.y); p0[6] = f2bf(b.z); p0[7] = f2bf(b.w);
        p1[0] = f2bf(c.x); p1[1] = f2bf(c.y); p1[2] = f2bf(c.z); p1[3] = f2bf(c.w);
        p1[4] = f2bf(d.x); p1[5] = f2bf(d.y); p1[6] = f2bf(d.z); p1[7] = f2bf(d.w);
        *(bf16x8*)(x_bf + base) = p0;
        *(bf16x8*)(x_bf + base + 8) = p1;
    }
}

// ---------------------------------------------------------------------------
// Kernel 2: per 32-token tile, 8 waves. Operand-swapped MFMA, 2 token-frags
// per wave (register blocking: every weight-frag load feeds 2 MFMAs).
//   down: D[n][token] (waves = nq x kh) -> silu*gate -> a_s
//   up:   D[h][token] (wave = 256-col h chunk), float4 stores
// ---------------------------------------------------------------------------
template<bool XBF>
__global__ __launch_bounds__(512) void moe_mfma_kernel(
    const float* __restrict__ x, const short* __restrict__ x_bf,
    const float* __restrict__ gate_ws,
    const short* __restrict__ b1p, const short* __restrict__ b2p,
    float* __restrict__ out, int T)
{
    __shared__ float h_part[TB][132];    // 132 ≡ 4 (mod 32) dwords: 2-way max, free
    __shared__ short a_s[TB][136];       // 136 sh = 68 dw ≡ 4 (mod 32)
    __shared__ float gate_s[TB][NEXP];

    const int tid = threadIdx.x;
    const int w = tid >> 6, l = tid & 63;
    const int c = l & 15;                // MFMA col lane -> token within frag
    const int kblk = l >> 4;             // k-block / D row-group
    const int t0 = blockIdx.x * TB;

    if (tid < TB * NEXP)
        gate_s[tid >> 3][tid & 7] = gate_ws[(size_t)(t0 + (tid >> 3)) * NEXP + (tid & 7)];
    __syncthreads();

    // ---------------- DOWN: D[n][token], 2 t-frags ----------------
    const int nq = w & 3, kh = w >> 2;
    const int n0 = nq * 32;
    f32x4 acc00 = {0,0,0,0}, acc01 = {0,0,0,0}, acc10 = {0,0,0,0}, acc11 = {0,0,0,0};

    const float* __restrict__ xr0 = x + (size_t)(t0 + c) * HDIM;
    const float* __restrict__ xr1 = x + (size_t)(t0 + 16 + c) * HDIM;
    const short* __restrict__ xb0 = x_bf + (size_t)(t0 + c) * HDIM;
    const short* __restrict__ xb1 = x_bf + (size_t)(t0 + 16 + c) * HDIM;

    for (int s = 0; s < 32; ++s) {
        const int k0 = kh * 1024 + s * 32;
        const int ka = k0 + kblk * 8;
        bf16x8 xf0, xf1;
        if (XBF) {
            xf0 = *(const bf16x8*)(xb0 + ka);
            xf1 = *(const bf16x8*)(xb1 + ka);
        } else {
            float4 a0 = *(const float4*)(xr0 + ka);
            float4 a1 = *(const float4*)(xr0 + ka + 4);
            float4 b0 = *(const float4*)(xr1 + ka);
            float4 b1 = *(const float4*)(xr1 + ka + 4);
            xf0[0]=f2bf(a0.x); xf0[1]=f2bf(a0.y); xf0[2]=f2bf(a0.z); xf0[3]=f2bf(a0.w);
            xf0[4]=f2bf(a1.x); xf0[5]=f2bf(a1.y); xf0[6]=f2bf(a1.z); xf0[7]=f2bf(a1.w);
            xf1[0]=f2bf(b0.x); xf1[1]=f2bf(b0.y); xf1[2]=f2bf(b0.z); xf1[3]=f2bf(b0.w);
            xf1[4]=f2bf(b1.x); xf1[5]=f2bf(b1.y); xf1[6]=f2bf(b1.z); xf1[7]=f2bf(b1.w);
        }
        const short* __restrict__ bbase = b1p + ((size_t)(k0 >> 3) + kblk) * 1024;
        bf16x8 wf0 = *(const bf16x8*)(bbase + (n0 + c) * 8);
        bf16x8 wf1 = *(const bf16x8*)(bbase + (n0 + 16 + c) * 8);
        acc00 = __builtin_amdgcn_mfma_f32_16x16x32_bf16(wf0, xf0, acc00, 0, 0, 0);
        acc01 = __builtin_amdgcn_mfma_f32_16x16x32_bf16(wf0, xf1, acc01, 0, 0, 0);
        acc10 = __builtin_amdgcn_mfma_f32_16x16x32_bf16(wf1, xf0, acc10, 0, 0, 0);
        acc11 = __builtin_amdgcn_mfma_f32_16x16x32_bf16(wf1, xf1, acc11, 0, 0, 0);
    }

    // D: col=c(token), row=kblk*4+r -> n = n0 (+16) + kblk*4 + r
    if (kh == 1) {
        *(f32x4*)&h_part[c][n0 + kblk * 4]           = acc00;
        *(f32x4*)&h_part[16 + c][n0 + kblk * 4]      = acc01;
        *(f32x4*)&h_part[c][n0 + 16 + kblk * 4]      = acc10;
        *(f32x4*)&h_part[16 + c][n0 + 16 + kblk * 4] = acc11;
    }
    __syncthreads();
    if (kh == 0) {
        const int e0 = nq * 2, e1 = nq * 2 + 1;
        #pragma unroll
        for (int tf = 0; tf < 2; ++tf) {
            const int trow = tf * 16 + c;
            const f32x4 pa = *(const f32x4*)&h_part[trow][n0 + kblk * 4];
            const f32x4 pb = *(const f32x4*)&h_part[trow][n0 + 16 + kblk * 4];
            const f32x4 da = tf ? acc01 : acc00;
            const f32x4 db = tf ? acc11 : acc10;
            const float g0 = gate_s[trow][e0], g1 = gate_s[trow][e1];
            short r0[4], r1[4];
            #pragma unroll
            for (int r = 0; r < 4; ++r) {
                const float h0v = da[r] + pa[r];
                const float h1v = db[r] + pb[r];
                r0[r] = f2bf(h0v / (1.f + expf(-h0v)) * g0);
                r1[r] = f2bf(h1v / (1.f + expf(-h1v)) * g1);
            }
            *(uint2*)&a_s[trow][n0 + kblk * 4] =
                make_uint2(((unsigned short)r0[0]) | ((unsigned)(unsigned short)r0[1] << 16),
                           ((unsigned short)r0[2]) | ((unsigned)(unsigned short)r0[3] << 16));
            *(uint2*)&a_s[trow][n0 + 16 + kblk * 4] =
                make_uint2(((unsigned short)r1[0]) | ((unsigned)(unsigned short)r1[1] << 16),
                           ((unsigned short)r1[2]) | ((unsigned)(unsigned short)r1[3] << 16));
        }
    }
    __syncthreads();

    // ---------------- UP: D[h][token], 16 h-frags x 2 t-frags ----------------
    const int h0 = w * 256;
    f32x4 acc[2][16];
    #pragma unroll
    for (int tf = 0; tf < 2; ++tf)
        #pragma unroll
        for (int f = 0; f < 16; ++f) acc[tf][f] = (f32x4){0,0,0,0};

    for (int s = 0; s < 4; ++s) {
        bf16x8 af0 = *(const bf16x8*)(&a_s[c][s * 32 + kblk * 8]);
        bf16x8 af1 = *(const bf16x8*)(&a_s[16 + c][s * 32 + kblk * 8]);
        const short* __restrict__ bbase = b2p + ((size_t)(s * 4) + kblk) * 16384;
        #pragma unroll
        for (int f = 0; f < 16; ++f) {
            bf16x8 wfr = *(const bf16x8*)(bbase + (size_t)(h0 + f * 16 + c) * 8);
            acc[0][f] = __builtin_amdgcn_mfma_f32_16x16x32_bf16(wfr, af0, acc[0][f], 0, 0, 0);
            acc[1][f] = __builtin_amdgcn_mfma_f32_16x16x32_bf16(wfr, af1, acc[1][f], 0, 0, 0);
        }
    }
    // lane holds 4 consecutive h (rows kblk*4+r) for tokens c, 16+c
    float* __restrict__ o0 = out + (size_t)(t0 + c) * HDIM;
    float* __restrict__ o1 = out + (size_t)(t0 + 16 + c) * HDIM;
    #pragma unroll
    for (int f = 0; f < 16; ++f) {
        *(f32x4*)(o0 + h0 + f * 16 + kblk * 4) = acc[0][f];
        *(f32x4*)(o1 + h0 + f * 16 + kblk * 4) = acc[1][f];
    }
}

extern "C" void kernel_launch(void* const* d_in, const int* in_sizes, int n_in,
                              void* d_out, int out_size, void* d_ws, size_t ws_size,
                              hipStream_t stream) {
    const float* x  = (const float*)d_in[0];
    const float* rw = (const float*)d_in[1];
    const float* dw = (const float*)d_in[2];
    const float* uw = (const float*)d_in[3];
    float* out = (float*)d_out;
    const int T = in_sizes[0] / HDIM;   // 8192 tokens

    // ws layout: gate (T*8*4 = 256KB) | b1p (512KB) | b2p (512KB) | x_bf (T*H*2)
    float* gate_ws = (float*)d_ws;
    short* b1p = (short*)((char*)d_ws + (size_t)T * NEXP * 4);
    short* b2p = (short*)((char*)d_ws + (size_t)T * NEXP * 4 + 524288);
    short* x_bf = (short*)((char*)d_ws + (size_t)T * NEXP * 4 + 1048576);

    const size_t ws_needed = (size_t)T * NEXP * 4 + 1048576 + (size_t)T * HDIM * 2;
    const bool use_xbf = (ws_size >= ws_needed);

    const int routerBlocks = T / 4;                          // 2048
    const int xcvtBlocks = use_xbf ? (T * HDIM / (256 * 16)) : 0;   // 4096
    prep_kernel<<<routerBlocks + 256 + xcvtBlocks, 256, 0, stream>>>(
        x, rw, dw, uw, gate_ws, b1p, b2p, x_bf, T, routerBlocks);

    if (use_xbf)
        moe_mfma_kernel<true><<<T / TB, 512, 0, stream>>>(x, x_bf, gate_ws, b1p, b2p, out, T);
    else
        moe_mfma_kernel<false><<<T / TB, 512, 0, stream>>>(x, x_bf, gate_ws, b1p, b2p, out, T);
}